// Round 2
// baseline (272.929 us; speedup 1.0000x reference)
//
#include <hip/hip_runtime.h>
#include <hip/hip_bf16.h>

typedef __attribute__((ext_vector_type(8))) short bf16x8;
typedef __attribute__((ext_vector_type(4))) short s16x4;
typedef __attribute__((ext_vector_type(4))) float f32x4;

__device__ __forceinline__ short f2bf(float f) {
    unsigned int u = __builtin_bit_cast(unsigned int, f);
    u += 0x7fffu + ((u >> 16) & 1u);
    return (short)(u >> 16);
}

// ---------------- fp32 -> bf16 convert ----------------
__global__ __launch_bounds__(256) void cvt_kernel(const float* __restrict__ in,
                                                  short* __restrict__ out, int n4) {
    int i = blockIdx.x * 256 + threadIdx.x;
    if (i >= n4) return;
    float4 v = reinterpret_cast<const float4*>(in)[i];
    s16x4 r = { f2bf(v.x), f2bf(v.y), f2bf(v.z), f2bf(v.w) };
    reinterpret_cast<s16x4*>(out)[i] = r;
}

// ---------------- QKV GEMM (+RoPE epilogue) ----------------
// X: (4096,1024) bf16 row-major; W: (3072,1024) bf16 row-major (used as W^T)
// Writes Q,K,V bf16 in (B=2, H=16, S=2048, dh=64) layout. Q scaled by 0.125.
#define LDP 72

__global__ __launch_bounds__(256) void gemm_qkv_rope(
    const short* __restrict__ X, const short* __restrict__ W,
    const float* __restrict__ cosT, const float* __restrict__ sinT,
    short* __restrict__ Qo, short* __restrict__ Ko, short* __restrict__ Vo) {
    __shared__ short As[128][LDP];
    __shared__ short Bs[128][LDP];
    const int tid = threadIdx.x;
    const int lane = tid & 63;
    const int w = tid >> 6;
    const int wr = w >> 1, wc = w & 1;
    const int m0 = blockIdx.y * 128;
    const int n0 = blockIdx.x * 128;
    const int K = 1024;

    f32x4 acc[4][4];
#pragma unroll
    for (int i = 0; i < 4; i++)
#pragma unroll
        for (int j = 0; j < 4; j++) acc[i][j] = {0.f, 0.f, 0.f, 0.f};

    const int srow = tid >> 1;
    const int scol = (tid & 1) * 32;

    for (int k0 = 0; k0 < K; k0 += 64) {
        __syncthreads();
        {
            const short* srcA = X + (size_t)(m0 + srow) * K + k0 + scol;
            const short* srcB = W + (size_t)(n0 + srow) * K + k0 + scol;
#pragma unroll
            for (int i = 0; i < 4; i++)
                *reinterpret_cast<bf16x8*>(&As[srow][scol + i * 8]) =
                    *reinterpret_cast<const bf16x8*>(srcA + i * 8);
#pragma unroll
            for (int i = 0; i < 4; i++)
                *reinterpret_cast<bf16x8*>(&Bs[srow][scol + i * 8]) =
                    *reinterpret_cast<const bf16x8*>(srcB + i * 8);
        }
        __syncthreads();
#pragma unroll
        for (int kk = 0; kk < 2; kk++) {
            bf16x8 a[4], b[4];
#pragma unroll
            for (int mi = 0; mi < 4; mi++)
                a[mi] = *reinterpret_cast<const bf16x8*>(
                    &As[wr * 64 + mi * 16 + (lane & 15)][kk * 32 + (lane >> 4) * 8]);
#pragma unroll
            for (int ni = 0; ni < 4; ni++)
                b[ni] = *reinterpret_cast<const bf16x8*>(
                    &Bs[wc * 64 + ni * 16 + (lane & 15)][kk * 32 + (lane >> 4) * 8]);
#pragma unroll
            for (int mi = 0; mi < 4; mi++)
#pragma unroll
                for (int ni = 0; ni < 4; ni++)
                    acc[mi][ni] = __builtin_amdgcn_mfma_f32_16x16x32_bf16(
                        a[mi], b[ni], acc[mi][ni], 0, 0, 0);
        }
    }

    const int region = n0 >> 10;  // 0=q, 1=k, 2=v (tileN is region-uniform)
#pragma unroll
    for (int mi = 0; mi < 4; mi++) {
#pragma unroll
        for (int r = 0; r < 4; r++) {
            const int m = m0 + wr * 64 + mi * 16 + ((lane >> 4) << 2) + r;
            const int b_ = m >> 11;
            const int s_ = m & 2047;
#pragma unroll
            for (int ni = 0; ni < 4; ni++) {
                float v = acc[mi][ni][r];
                const int n = n0 + wc * 64 + ni * 16 + (lane & 15);
                const int c = n & 1023;
                const int h = c >> 6;
                const int d = c & 63;
                const size_t oidx = ((size_t)(b_ * 16 + h) * 2048 + s_) * 64 + d;
                if (region == 2) {
                    Vo[oidx] = f2bf(v);
                } else {
                    float other = __shfl_xor(v, 1, 64);
                    const int i2 = d >> 1;
                    float cs = cosT[s_ * 32 + i2];
                    float sn = sinT[s_ * 32 + i2];
                    float outv = (d & 1) ? (v * cs + other * sn) : (v * cs - other * sn);
                    if (region == 0) {
                        Qo[oidx] = f2bf(outv * 0.125f);
                    } else {
                        Ko[oidx] = f2bf(outv);
                    }
                }
            }
        }
    }
}

// ---------------- Flash attention (causal) ----------------
// Q,K,V: (2,16,2048,64) bf16 (Q pre-scaled). O: (2,2048,1024) bf16.
__global__ __launch_bounds__(256) void attn_kernel(
    const short* __restrict__ Q, const short* __restrict__ K,
    const short* __restrict__ V, short* __restrict__ O) {
    __shared__ short Qs[64][LDP];
    __shared__ short Ks[64][LDP];
    __shared__ short Vts[64][LDP];
    __shared__ short Ps[4][16][LDP];

    const int tid = threadIdx.x;
    const int lane = tid & 63;
    const int w = tid >> 6;
    const int qt = blockIdx.x;
    const int bh = blockIdx.y;
    const int b_ = bh >> 4, h = bh & 15;
    const size_t base = (size_t)bh * 2048 * 64;
    const int qbase = qt * 64;

    {
        const int row = tid >> 2, cb = (tid & 3) * 16;
        const short* src = Q + base + (size_t)(qbase + row) * 64 + cb;
        *reinterpret_cast<bf16x8*>(&Qs[row][cb]) = *reinterpret_cast<const bf16x8*>(src);
        *reinterpret_cast<bf16x8*>(&Qs[row][cb + 8]) = *reinterpret_cast<const bf16x8*>(src + 8);
    }

    float m_r[4], l_r[4];
    f32x4 o_acc[4];
#pragma unroll
    for (int r = 0; r < 4; r++) { m_r[r] = -1e30f; l_r[r] = 0.f; }
#pragma unroll
    for (int db = 0; db < 4; db++) o_acc[db] = {0.f, 0.f, 0.f, 0.f};

    for (int j = 0; j <= qt; j++) {
        const int jbase = j * 64;
        __syncthreads();
        {
            const int row = tid >> 2, cb = (tid & 3) * 16;
            const short* src = K + base + (size_t)(jbase + row) * 64 + cb;
            *reinterpret_cast<bf16x8*>(&Ks[row][cb]) = *reinterpret_cast<const bf16x8*>(src);
            *reinterpret_cast<bf16x8*>(&Ks[row][cb + 8]) = *reinterpret_cast<const bf16x8*>(src + 8);
        }
#pragma unroll
        for (int half = 0; half < 2; half++) {
            const int kv = (tid >> 3) + half * 32;
            const int db8 = (tid & 7) * 8;
            bf16x8 v = *reinterpret_cast<const bf16x8*>(V + base + (size_t)(jbase + kv) * 64 + db8);
#pragma unroll
            for (int i = 0; i < 8; i++) Vts[db8 + i][kv] = v[i];
        }
        __syncthreads();

        f32x4 sc[4];
#pragma unroll
        for (int nb = 0; nb < 4; nb++) sc[nb] = {0.f, 0.f, 0.f, 0.f};
#pragma unroll
        for (int kk = 0; kk < 2; kk++) {
            bf16x8 a = *reinterpret_cast<const bf16x8*>(
                &Qs[w * 16 + (lane & 15)][kk * 32 + (lane >> 4) * 8]);
#pragma unroll
            for (int nb = 0; nb < 4; nb++) {
                bf16x8 bfr = *reinterpret_cast<const bf16x8*>(
                    &Ks[nb * 16 + (lane & 15)][kk * 32 + (lane >> 4) * 8]);
                sc[nb] = __builtin_amdgcn_mfma_f32_16x16x32_bf16(a, bfr, sc[nb], 0, 0, 0);
            }
        }
        if (j == qt) {
            // local q row within the 64-row tile INCLUDES the wave offset w*16
            const int s_ = w * 16 + ((lane >> 4) << 2);
#pragma unroll
            for (int nb = 0; nb < 4; nb++) {
                const int t_ = nb * 16 + (lane & 15);
#pragma unroll
                for (int r = 0; r < 4; r++) {
                    if (t_ > s_ + r) sc[nb][r] = -1e30f;
                }
            }
        }

        float p[4][4];
#pragma unroll
        for (int r = 0; r < 4; r++) {
            float mx = fmaxf(fmaxf(sc[0][r], sc[1][r]), fmaxf(sc[2][r], sc[3][r]));
#pragma unroll
            for (int off = 1; off < 16; off <<= 1) mx = fmaxf(mx, __shfl_xor(mx, off, 64));
            const float mnew = fmaxf(m_r[r], mx);
            const float alpha = __expf(m_r[r] - mnew);
            m_r[r] = mnew;
            float rs = 0.f;
#pragma unroll
            for (int nb = 0; nb < 4; nb++) {
                float e = __expf(sc[nb][r] - mnew);
                p[nb][r] = e;
                rs += e;
            }
#pragma unroll
            for (int off = 1; off < 16; off <<= 1) rs += __shfl_xor(rs, off, 64);
            l_r[r] = l_r[r] * alpha + rs;
#pragma unroll
            for (int db = 0; db < 4; db++) o_acc[db][r] *= alpha;
        }
#pragma unroll
        for (int nb = 0; nb < 4; nb++)
#pragma unroll
            for (int r = 0; r < 4; r++)
                Ps[w][((lane >> 4) << 2) + r][nb * 16 + (lane & 15)] = f2bf(p[nb][r]);
#pragma unroll
        for (int kk = 0; kk < 2; kk++) {
            bf16x8 pa = *reinterpret_cast<const bf16x8*>(
                &Ps[w][lane & 15][kk * 32 + (lane >> 4) * 8]);
#pragma unroll
            for (int db = 0; db < 4; db++) {
                bf16x8 vb = *reinterpret_cast<const bf16x8*>(
                    &Vts[db * 16 + (lane & 15)][kk * 32 + (lane >> 4) * 8]);
                o_acc[db] = __builtin_amdgcn_mfma_f32_16x16x32_bf16(pa, vb, o_acc[db], 0, 0, 0);
            }
        }
    }

    short* Op = O + ((size_t)b_ * 2048) * 1024 + (size_t)h * 64;
#pragma unroll
    for (int r = 0; r < 4; r++) {
        const float inv = 1.f / l_r[r];
        const int row = qbase + w * 16 + ((lane >> 4) << 2) + r;
#pragma unroll
        for (int db = 0; db < 4; db++)
            Op[(size_t)row * 1024 + db * 16 + (lane & 15)] = f2bf(o_acc[db][r] * inv);
    }
}

// ---------------- Out GEMM ----------------
// A: (4096,1024) bf16, W: (1024,1024) bf16 (used as W^T), C: fp32
__global__ __launch_bounds__(256) void gemm_out(
    const short* __restrict__ A, const short* __restrict__ W,
    float* __restrict__ C) {
    __shared__ short As[128][LDP];
    __shared__ short Bs[128][LDP];
    const int tid = threadIdx.x;
    const int lane = tid & 63;
    const int w = tid >> 6;
    const int wr = w >> 1, wc = w & 1;
    const int m0 = blockIdx.y * 128;
    const int n0 = blockIdx.x * 128;
    const int K = 1024;

    f32x4 acc[4][4];
#pragma unroll
    for (int i = 0; i < 4; i++)
#pragma unroll
        for (int j = 0; j < 4; j++) acc[i][j] = {0.f, 0.f, 0.f, 0.f};

    const int srow = tid >> 1;
    const int scol = (tid & 1) * 32;

    for (int k0 = 0; k0 < K; k0 += 64) {
        __syncthreads();
        {
            const short* srcA = A + (size_t)(m0 + srow) * K + k0 + scol;
            const short* srcB = W + (size_t)(n0 + srow) * K + k0 + scol;
#pragma unroll
            for (int i = 0; i < 4; i++)
                *reinterpret_cast<bf16x8*>(&As[srow][scol + i * 8]) =
                    *reinterpret_cast<const bf16x8*>(srcA + i * 8);
#pragma unroll
            for (int i = 0; i < 4; i++)
                *reinterpret_cast<bf16x8*>(&Bs[srow][scol + i * 8]) =
                    *reinterpret_cast<const bf16x8*>(srcB + i * 8);
        }
        __syncthreads();
#pragma unroll
        for (int kk = 0; kk < 2; kk++) {
            bf16x8 a[4], b[4];
#pragma unroll
            for (int mi = 0; mi < 4; mi++)
                a[mi] = *reinterpret_cast<const bf16x8*>(
                    &As[wr * 64 + mi * 16 + (lane & 15)][kk * 32 + (lane >> 4) * 8]);
#pragma unroll
            for (int ni = 0; ni < 4; ni++)
                b[ni] = *reinterpret_cast<const bf16x8*>(
                    &Bs[wc * 64 + ni * 16 + (lane & 15)][kk * 32 + (lane >> 4) * 8]);
#pragma unroll
            for (int mi = 0; mi < 4; mi++)
#pragma unroll
                for (int ni = 0; ni < 4; ni++)
                    acc[mi][ni] = __builtin_amdgcn_mfma_f32_16x16x32_bf16(
                        a[mi], b[ni], acc[mi][ni], 0, 0, 0);
        }
    }

#pragma unroll
    for (int mi = 0; mi < 4; mi++) {
#pragma unroll
        for (int r = 0; r < 4; r++) {
            const int m = m0 + wr * 64 + mi * 16 + ((lane >> 4) << 2) + r;
#pragma unroll
            for (int ni = 0; ni < 4; ni++) {
                const int n = n0 + wc * 64 + ni * 16 + (lane & 15);
                C[(size_t)m * 1024 + n] = acc[mi][ni][r];
            }
        }
    }
}

extern "C" void kernel_launch(void* const* d_in, const int* in_sizes, int n_in,
                              void* d_out, int out_size, void* d_ws, size_t ws_size,
                              hipStream_t stream) {
    const float* x = (const float*)d_in[0];
    const float* wQKV = (const float*)d_in[1];
    const float* wOut = (const float*)d_in[2];
    const float* cosT = (const float*)d_in[3];
    const float* sinT = (const float*)d_in[4];
    float* out = (float*)d_out;

    char* ws = (char*)d_ws;
    const size_t MB = 1024 * 1024;
    short* xb    = (short*)(ws);             // 4M elems, 8MB
    short* wqkvb = (short*)(ws + 8 * MB);    // 3M elems, 6MB
    short* woutb = (short*)(ws + 14 * MB);   // 1M elems, 2MB
    short* Qb    = (short*)(ws + 16 * MB);   // 4M elems, 8MB
    short* Kb    = (short*)(ws + 24 * MB);
    short* Vb    = (short*)(ws + 32 * MB);
    short* Ob    = (short*)(ws + 40 * MB);   // total 48MB

    cvt_kernel<<<4096, 256, 0, stream>>>(x, xb, 1048576);
    cvt_kernel<<<3072, 256, 0, stream>>>(wQKV, wqkvb, 786432);
    cvt_kernel<<<1024, 256, 0, stream>>>(wOut, woutb, 262144);

    gemm_qkv_rope<<<dim3(24, 32), 256, 0, stream>>>(xb, wqkvb, cosT, sinT, Qb, Kb, Vb);
    attn_kernel<<<dim3(32, 32), 256, 0, stream>>>(Qb, Kb, Vb, Ob);
    gemm_out<<<dim3(8, 32), 256, 0, stream>>>(Ob, woutb, out);
}

// Round 3
// 189.369 us; speedup vs baseline: 1.4413x; 1.4413x over previous
//
#include <hip/hip_runtime.h>
#include <hip/hip_bf16.h>

typedef __attribute__((ext_vector_type(8))) short bf16x8;
typedef __attribute__((ext_vector_type(4))) short s16x4;
typedef __attribute__((ext_vector_type(4))) float f32x4;

__device__ __forceinline__ short f2bf(float f) {
    unsigned int u = __builtin_bit_cast(unsigned int, f);
    u += 0x7fffu + ((u >> 16) & 1u);
    return (short)(u >> 16);
}

// ---------------- fp32 -> bf16 convert ----------------
__global__ __launch_bounds__(256) void cvt_kernel(const float* __restrict__ in,
                                                  short* __restrict__ out, int n4) {
    int i = blockIdx.x * 256 + threadIdx.x;
    if (i >= n4) return;
    float4 v = reinterpret_cast<const float4*>(in)[i];
    s16x4 r = { f2bf(v.x), f2bf(v.y), f2bf(v.z), f2bf(v.w) };
    reinterpret_cast<s16x4*>(out)[i] = r;
}

#define LDP 72

// ---------------- QKV GEMM (+RoPE epilogue) ----------------
__global__ __launch_bounds__(256) void gemm_qkv_rope(
    const short* __restrict__ X, const short* __restrict__ W,
    const float* __restrict__ cosT, const float* __restrict__ sinT,
    short* __restrict__ Qo, short* __restrict__ Ko, short* __restrict__ Vo) {
    __shared__ short As[128][LDP];
    __shared__ short Bs[128][LDP];
    const int tid = threadIdx.x;
    const int lane = tid & 63;
    const int w = tid >> 6;
    const int wr = w >> 1, wc = w & 1;
    const int m0 = blockIdx.y * 128;
    const int n0 = blockIdx.x * 128;
    const int K = 1024;

    f32x4 acc[4][4];
#pragma unroll
    for (int i = 0; i < 4; i++)
#pragma unroll
        for (int j = 0; j < 4; j++) acc[i][j] = {0.f, 0.f, 0.f, 0.f};

    const int srow = tid >> 1;
    const int scol = (tid & 1) * 32;

    for (int k0 = 0; k0 < K; k0 += 64) {
        __syncthreads();
        {
            const short* srcA = X + (size_t)(m0 + srow) * K + k0 + scol;
            const short* srcB = W + (size_t)(n0 + srow) * K + k0 + scol;
#pragma unroll
            for (int i = 0; i < 4; i++)
                *reinterpret_cast<bf16x8*>(&As[srow][scol + i * 8]) =
                    *reinterpret_cast<const bf16x8*>(srcA + i * 8);
#pragma unroll
            for (int i = 0; i < 4; i++)
                *reinterpret_cast<bf16x8*>(&Bs[srow][scol + i * 8]) =
                    *reinterpret_cast<const bf16x8*>(srcB + i * 8);
        }
        __syncthreads();
#pragma unroll
        for (int kk = 0; kk < 2; kk++) {
            bf16x8 a[4], b[4];
#pragma unroll
            for (int mi = 0; mi < 4; mi++)
                a[mi] = *reinterpret_cast<const bf16x8*>(
                    &As[wr * 64 + mi * 16 + (lane & 15)][kk * 32 + (lane >> 4) * 8]);
#pragma unroll
            for (int ni = 0; ni < 4; ni++)
                b[ni] = *reinterpret_cast<const bf16x8*>(
                    &Bs[wc * 64 + ni * 16 + (lane & 15)][kk * 32 + (lane >> 4) * 8]);
#pragma unroll
            for (int mi = 0; mi < 4; mi++)
#pragma unroll
                for (int ni = 0; ni < 4; ni++)
                    acc[mi][ni] = __builtin_amdgcn_mfma_f32_16x16x32_bf16(
                        a[mi], b[ni], acc[mi][ni], 0, 0, 0);
        }
    }

    const int region = n0 >> 10;  // 0=q, 1=k, 2=v (tileN is region-uniform)
#pragma unroll
    for (int mi = 0; mi < 4; mi++) {
#pragma unroll
        for (int r = 0; r < 4; r++) {
            const int m = m0 + wr * 64 + mi * 16 + ((lane >> 4) << 2) + r;
            const int b_ = m >> 11;
            const int s_ = m & 2047;
#pragma unroll
            for (int ni = 0; ni < 4; ni++) {
                float v = acc[mi][ni][r];
                const int n = n0 + wc * 64 + ni * 16 + (lane & 15);
                const int c = n & 1023;
                const int h = c >> 6;
                const int d = c & 63;
                const size_t oidx = ((size_t)(b_ * 16 + h) * 2048 + s_) * 64 + d;
                if (region == 2) {
                    Vo[oidx] = f2bf(v);
                } else {
                    float other = __shfl_xor(v, 1, 64);
                    const int i2 = d >> 1;
                    float cs = cosT[s_ * 32 + i2];
                    float sn = sinT[s_ * 32 + i2];
                    float outv = (d & 1) ? (v * cs + other * sn) : (v * cs - other * sn);
                    if (region == 0) {
                        Qo[oidx] = f2bf(outv * 0.125f);
                    } else {
                        Ko[oidx] = f2bf(outv);
                    }
                }
            }
        }
    }
}

// ---------------- Flash attention (causal, paired q-tiles) ----------------
// Q,K,V: (2,16,2048,64) bf16 (Q pre-scaled). O: (2,2048,1024) bf16.
// Block handles q-tiles (pi, 31-pi): every block does exactly 33 tile-computes.
// V^T in LDS uses column XOR-swizzle: elem (d,t) at d*LDP + (t ^ ((d>>3&7)<<3)).

__device__ __forceinline__ void attn_tile_compute(
    const short* __restrict__ Qs, const short* __restrict__ Ks,
    const short* __restrict__ Vts, short* __restrict__ Pw,
    const int lane, const int w, const bool diag,
    float* __restrict__ m_r, float* __restrict__ l_r, f32x4* __restrict__ o_acc) {
    const int lo = lane & 15, hi = lane >> 4;

    f32x4 sc[4];
#pragma unroll
    for (int nb = 0; nb < 4; nb++) sc[nb] = {0.f, 0.f, 0.f, 0.f};
#pragma unroll
    for (int kk = 0; kk < 2; kk++) {
        bf16x8 a = *reinterpret_cast<const bf16x8*>(&Qs[(w * 16 + lo) * LDP + kk * 32 + hi * 8]);
#pragma unroll
        for (int nb = 0; nb < 4; nb++) {
            bf16x8 b = *reinterpret_cast<const bf16x8*>(&Ks[(nb * 16 + lo) * LDP + kk * 32 + hi * 8]);
            sc[nb] = __builtin_amdgcn_mfma_f32_16x16x32_bf16(a, b, sc[nb], 0, 0, 0);
        }
    }
    if (diag) {
        const int s_ = w * 16 + (hi << 2);
#pragma unroll
        for (int nb = 0; nb < 4; nb++) {
            const int t_ = nb * 16 + lo;
#pragma unroll
            for (int r = 0; r < 4; r++)
                if (t_ > s_ + r) sc[nb][r] = -1e30f;
        }
    }

    float p[4][4];
#pragma unroll
    for (int r = 0; r < 4; r++) {
        float mx = fmaxf(fmaxf(sc[0][r], sc[1][r]), fmaxf(sc[2][r], sc[3][r]));
#pragma unroll
        for (int off = 1; off < 16; off <<= 1) mx = fmaxf(mx, __shfl_xor(mx, off, 64));
        const float mnew = fmaxf(m_r[r], mx);
        const float alpha = __expf(m_r[r] - mnew);
        m_r[r] = mnew;
        float rs = 0.f;
#pragma unroll
        for (int nb = 0; nb < 4; nb++) {
            float e = __expf(sc[nb][r] - mnew);
            p[nb][r] = e;
            rs += e;
        }
#pragma unroll
        for (int off = 1; off < 16; off <<= 1) rs += __shfl_xor(rs, off, 64);
        l_r[r] = l_r[r] * alpha + rs;
#pragma unroll
        for (int db = 0; db < 4; db++) o_acc[db][r] *= alpha;
    }
#pragma unroll
    for (int nb = 0; nb < 4; nb++)
#pragma unroll
        for (int r = 0; r < 4; r++)
            Pw[((hi << 2) + r) * LDP + nb * 16 + lo] = f2bf(p[nb][r]);
#pragma unroll
    for (int kk = 0; kk < 2; kk++) {
        bf16x8 pa = *reinterpret_cast<const bf16x8*>(&Pw[lo * LDP + kk * 32 + hi * 8]);
#pragma unroll
        for (int db = 0; db < 4; db++) {
            const int d = db * 16 + lo;
            const int tsw = (kk * 32 + hi * 8) ^ ((((d >> 3) & 7)) << 3);
            bf16x8 vb = *reinterpret_cast<const bf16x8*>(&Vts[d * LDP + tsw]);
            o_acc[db] = __builtin_amdgcn_mfma_f32_16x16x32_bf16(pa, vb, o_acc[db], 0, 0, 0);
        }
    }
}

__global__ __launch_bounds__(256) void attn_kernel(
    const short* __restrict__ Q, const short* __restrict__ K,
    const short* __restrict__ V, short* __restrict__ O) {
    __shared__ short Qa[64][LDP];
    __shared__ short Qb[64][LDP];
    __shared__ short Ks[64][LDP];
    __shared__ short Vts[64][LDP];
    __shared__ short Ps[4][16][LDP];

    const int tid = threadIdx.x;
    const int lane = tid & 63;
    const int w = tid >> 6;
    const int pi = blockIdx.x;          // 0..15
    const int qa = pi, qb = 31 - pi;    // paired q-tiles
    const int bh = blockIdx.y;
    const int b_ = bh >> 4, h = bh & 15;
    const size_t base = (size_t)bh * 2048 * 64;

    {
        const int row = tid >> 2, cb = (tid & 3) * 16;
        const short* srcA = Q + base + (size_t)(qa * 64 + row) * 64 + cb;
        const short* srcB = Q + base + (size_t)(qb * 64 + row) * 64 + cb;
        *reinterpret_cast<bf16x8*>(&Qa[row][cb]) = *reinterpret_cast<const bf16x8*>(srcA);
        *reinterpret_cast<bf16x8*>(&Qa[row][cb + 8]) = *reinterpret_cast<const bf16x8*>(srcA + 8);
        *reinterpret_cast<bf16x8*>(&Qb[row][cb]) = *reinterpret_cast<const bf16x8*>(srcB);
        *reinterpret_cast<bf16x8*>(&Qb[row][cb + 8]) = *reinterpret_cast<const bf16x8*>(srcB + 8);
    }

    float m_a[4], l_a[4], m_b[4], l_b[4];
    f32x4 o_a[4], o_b[4];
#pragma unroll
    for (int r = 0; r < 4; r++) { m_a[r] = -1e30f; l_a[r] = 0.f; m_b[r] = -1e30f; l_b[r] = 0.f; }
#pragma unroll
    for (int db = 0; db < 4; db++) { o_a[db] = {0.f, 0.f, 0.f, 0.f}; o_b[db] = {0.f, 0.f, 0.f, 0.f}; }

    for (int j = 0; j <= qb; j++) {
        const int jbase = j * 64;
        __syncthreads();
        {
            const int row = tid >> 2, cb = (tid & 3) * 16;
            const short* src = K + base + (size_t)(jbase + row) * 64 + cb;
            *reinterpret_cast<bf16x8*>(&Ks[row][cb]) = *reinterpret_cast<const bf16x8*>(src);
            *reinterpret_cast<bf16x8*>(&Ks[row][cb + 8]) = *reinterpret_cast<const bf16x8*>(src + 8);
        }
#pragma unroll
        for (int half = 0; half < 2; half++) {
            const int kv = (tid >> 3) + half * 32;
            const int db8 = (tid & 7) * 8;
            const int swz = (tid & 7) << 3;   // = ((d>>3)&7)<<3 for d in [db8, db8+7]
            bf16x8 v = *reinterpret_cast<const bf16x8*>(V + base + (size_t)(jbase + kv) * 64 + db8);
            const int tsw = kv ^ swz;
#pragma unroll
            for (int i = 0; i < 8; i++) Vts[db8 + i][tsw] = v[i];
        }
        __syncthreads();

        attn_tile_compute(&Qb[0][0], &Ks[0][0], &Vts[0][0], &Ps[w][0][0],
                          lane, w, j == qb, m_b, l_b, o_b);
        if (j <= qa)
            attn_tile_compute(&Qa[0][0], &Ks[0][0], &Vts[0][0], &Ps[w][0][0],
                              lane, w, j == qa, m_a, l_a, o_a);
    }

    short* Op = O + ((size_t)b_ * 2048) * 1024 + (size_t)h * 64;
    const int lo = lane & 15, hi = lane >> 4;
#pragma unroll
    for (int r = 0; r < 4; r++) {
        const float inva = 1.f / l_a[r];
        const float invb = 1.f / l_b[r];
        const int rowa = qa * 64 + w * 16 + (hi << 2) + r;
        const int rowb = qb * 64 + w * 16 + (hi << 2) + r;
#pragma unroll
        for (int db = 0; db < 4; db++) {
            Op[(size_t)rowa * 1024 + db * 16 + lo] = f2bf(o_a[db][r] * inva);
            Op[(size_t)rowb * 1024 + db * 16 + lo] = f2bf(o_b[db][r] * invb);
        }
    }
}

// ---------------- Out GEMM ----------------
__global__ __launch_bounds__(256) void gemm_out(
    const short* __restrict__ A, const short* __restrict__ W,
    float* __restrict__ C) {
    __shared__ short As[128][LDP];
    __shared__ short Bs[128][LDP];
    const int tid = threadIdx.x;
    const int lane = tid & 63;
    const int w = tid >> 6;
    const int wr = w >> 1, wc = w & 1;
    const int m0 = blockIdx.y * 128;
    const int n0 = blockIdx.x * 128;
    const int K = 1024;

    f32x4 acc[4][4];
#pragma unroll
    for (int i = 0; i < 4; i++)
#pragma unroll
        for (int j = 0; j < 4; j++) acc[i][j] = {0.f, 0.f, 0.f, 0.f};

    const int srow = tid >> 1;
    const int scol = (tid & 1) * 32;

    for (int k0 = 0; k0 < K; k0 += 64) {
        __syncthreads();
        {
            const short* srcA = A + (size_t)(m0 + srow) * K + k0 + scol;
            const short* srcB = W + (size_t)(n0 + srow) * K + k0 + scol;
#pragma unroll
            for (int i = 0; i < 4; i++)
                *reinterpret_cast<bf16x8*>(&As[srow][scol + i * 8]) =
                    *reinterpret_cast<const bf16x8*>(srcA + i * 8);
#pragma unroll
            for (int i = 0; i < 4; i++)
                *reinterpret_cast<bf16x8*>(&Bs[srow][scol + i * 8]) =
                    *reinterpret_cast<const bf16x8*>(srcB + i * 8);
        }
        __syncthreads();
#pragma unroll
        for (int kk = 0; kk < 2; kk++) {
            bf16x8 a[4], b[4];
#pragma unroll
            for (int mi = 0; mi < 4; mi++)
                a[mi] = *reinterpret_cast<const bf16x8*>(
                    &As[wr * 64 + mi * 16 + (lane & 15)][kk * 32 + (lane >> 4) * 8]);
#pragma unroll
            for (int ni = 0; ni < 4; ni++)
                b[ni] = *reinterpret_cast<const bf16x8*>(
                    &Bs[wc * 64 + ni * 16 + (lane & 15)][kk * 32 + (lane >> 4) * 8]);
#pragma unroll
            for (int mi = 0; mi < 4; mi++)
#pragma unroll
                for (int ni = 0; ni < 4; ni++)
                    acc[mi][ni] = __builtin_amdgcn_mfma_f32_16x16x32_bf16(
                        a[mi], b[ni], acc[mi][ni], 0, 0, 0);
        }
    }

#pragma unroll
    for (int mi = 0; mi < 4; mi++) {
#pragma unroll
        for (int r = 0; r < 4; r++) {
            const int m = m0 + wr * 64 + mi * 16 + ((lane >> 4) << 2) + r;
#pragma unroll
            for (int ni = 0; ni < 4; ni++) {
                const int n = n0 + wc * 64 + ni * 16 + (lane & 15);
                C[(size_t)m * 1024 + n] = acc[mi][ni][r];
            }
        }
    }
}

extern "C" void kernel_launch(void* const* d_in, const int* in_sizes, int n_in,
                              void* d_out, int out_size, void* d_ws, size_t ws_size,
                              hipStream_t stream) {
    const float* x = (const float*)d_in[0];
    const float* wQKV = (const float*)d_in[1];
    const float* wOut = (const float*)d_in[2];
    const float* cosT = (const float*)d_in[3];
    const float* sinT = (const float*)d_in[4];
    float* out = (float*)d_out;

    char* ws = (char*)d_ws;
    const size_t MB = 1024 * 1024;
    short* xb    = (short*)(ws);             // 4M elems, 8MB
    short* wqkvb = (short*)(ws + 8 * MB);    // 3M elems, 6MB
    short* woutb = (short*)(ws + 14 * MB);   // 1M elems, 2MB
    short* Qb    = (short*)(ws + 16 * MB);   // 4M elems, 8MB
    short* Kb    = (short*)(ws + 24 * MB);
    short* Vb    = (short*)(ws + 32 * MB);
    short* Ob    = (short*)(ws + 40 * MB);   // total 48MB

    cvt_kernel<<<4096, 256, 0, stream>>>(x, xb, 1048576);
    cvt_kernel<<<3072, 256, 0, stream>>>(wQKV, wqkvb, 786432);
    cvt_kernel<<<1024, 256, 0, stream>>>(wOut, woutb, 262144);

    gemm_qkv_rope<<<dim3(24, 32), 256, 0, stream>>>(xb, wqkvb, cosT, sinT, Qb, Kb, Vb);
    attn_kernel<<<dim3(16, 32), 256, 0, stream>>>(Qb, Kb, Vb, Ob);
    gemm_out<<<dim3(8, 32), 256, 0, stream>>>(Ob, woutb, out);
}